// Round 13
// baseline (1826.928 us; speedup 1.0000x reference)
//
#include <hip/hip_runtime.h>
#include <hip/hip_cooperative_groups.h>
#include <math.h>

namespace cg = cooperative_groups;

#define N_NODES 50000
#define N_EDGES 800000
#define NPAD 50176
#define HSTR 224   // hbuf row stride (floats): exactly 7 aligned 128B lines
// ecsbuf (NPAD+2 ints, ecsbuf[0]=0): counts at ecsbuf[1+d] (hist); post-scan
// ecsbuf[1+d] = start(d), never mutated again (rank-based fill).
// Readers: start(n) = ecsbuf[n+1], end(n) = ecsbuf[n+2].

typedef __attribute__((ext_vector_type(8))) short short8;
typedef __attribute__((ext_vector_type(4))) float f32x4;

// ---------------- helpers ----------------

__device__ __forceinline__ float fast_tanh(float x) {
    float e = __expf(2.0f * x);
    float r = __builtin_amdgcn_rcpf(e + 1.0f);
    return 1.0f - 2.0f * r;
}

__device__ __forceinline__ unsigned short rne_bf16(float x) {
    unsigned u = __builtin_bit_cast(unsigned, x);
    return (unsigned short)((u + 0x7FFFu + ((u >> 16) & 1u)) >> 16);
}

__device__ __forceinline__ void split_bf16(float x, unsigned short& hi, unsigned short& lo) {
    hi = rne_bf16(x);
    float hf = __builtin_bit_cast(float, (unsigned)hi << 16);
    lo = rne_bf16(x - hf);
}

__device__ __forceinline__ f32x4 mfma16(short8 a, short8 b, f32x4 c) {
    return __builtin_amdgcn_mfma_f32_16x16x32_bf16(a, b, c, 0, 0, 0);
}

__device__ __forceinline__ void wsplit_one(const float* __restrict__ W, int KIN, int LDA,
                                           unsigned short* __restrict__ WT_hi,
                                           unsigned short* __restrict__ WT_lo, int idx) {
    int n = idx / LDA;
    int k = idx - n * LDA;
    float v = (n < 220 && k < KIN) ? W[k * 220 + n] : 0.f;
    unsigned short hi, lo;
    split_bf16(v, hi, lo);
    WT_hi[idx] = hi;
    WT_lo[idx] = lo;
}

// workspace word offsets (shared host/device)
#define O_ECS      0         // 50432
#define O_DEGOUT   50432     // 50176
#define O_BSUM     100608    // 256
#define O_INVOUT   100864
#define O_INVIN    151040
#define O_SRCS     201216    // 800000
#define O_WT0H     1001216
#define O_WT0L     1004800
#define O_WT1H     1008384
#define O_WT1L     1033472
#define O_WT2H     1058560
#define O_WT2L     1083648
#define O_AHI      1108736   // 5619712 w (rank aliases first 800000 w; A22 = same region, after rank dead)
#define O_XS       4108736   // inside ahi slot, clear of rank/A22
#define O_ALO      6728448   // 5619712 w
#define O_HBUF     12348160  // 11200000 w
#define O_TMP10    23548160  // 500000 w

// ---------------- cooperative front-end ----------------
// One kernel replaces: memset, hist+rank+wsplit, scan1, scan_mid, scan3,
// post_scan{invsqrt|fill|prescale}, agg22_split — 7 dispatches -> 1.
// All phases are low-VGPR / 1KB-LDS so the cooperative grid runs at high
// occupancy (the r9 lesson: never couple latency-bound gathers to an
// occupancy-limited consumer — the fat GEMMs stay separate).
__global__ void k_front_coop(const int* __restrict__ ei, const float* __restrict__ x,
                             const float* __restrict__ W0, const float* __restrict__ W1,
                             const float* __restrict__ W2, int* __restrict__ ws) {
    cg::grid_group grid = cg::this_grid();
    int* ecsbuf = ws + O_ECS;
    int* deg_out = ws + O_DEGOUT;
    int* bsumA = ws + O_BSUM;
    float* inv_out = (float*)(ws + O_INVOUT);
    float* inv_in = (float*)(ws + O_INVIN);
    int* src_sorted = ws + O_SRCS;
    unsigned short* wt0h = (unsigned short*)(ws + O_WT0H);
    unsigned short* wt0l = (unsigned short*)(ws + O_WT0L);
    unsigned short* wt1h = (unsigned short*)(ws + O_WT1H);
    unsigned short* wt1l = (unsigned short*)(ws + O_WT1L);
    unsigned short* wt2h = (unsigned short*)(ws + O_WT2H);
    unsigned short* wt2l = (unsigned short*)(ws + O_WT2L);
    int* rank = ws + O_AHI;
    unsigned short* A_hi = (unsigned short*)(ws + O_AHI);
    unsigned short* A_lo = (unsigned short*)(ws + O_ALO);
    float* xs = (float*)(ws + O_XS);

    int tid = threadIdx.x;
    int nb = gridDim.x;
    __shared__ int s[256];

    // P0: zero ecsbuf + deg_out (contiguous 100608 words)
    for (int i = blockIdx.x * 256 + tid; i < 100608; i += nb * 256) ws[i] = 0;
    grid.sync();

    // P1: histogram + per-edge rank | weight splits (virtual blocks 0..3544)
    for (int v = blockIdx.x; v < 3545; v += nb) {
        if (v < 3125) {
            int e = v * 256 + tid;
            if (e < N_EDGES) {
                atomicAdd(&deg_out[ei[e]], 1);
                rank[e] = atomicAdd(&ecsbuf[1 + ei[N_EDGES + e]], 1);
            }
        } else if (v < 3153) {
            int idx = (v - 3125) * 256 + tid;
            if (idx < 224 * 32) wsplit_one(W0, 22, 32, wt0h, wt0l, idx);
        } else if (v < 3349) {
            int idx = (v - 3153) * 256 + tid;
            wsplit_one(W1, 220, 224, wt1h, wt1l, idx);
        } else {
            int idx = (v - 3349) * 256 + tid;
            wsplit_one(W2, 220, 224, wt2h, wt2l, idx);
        }
    }
    grid.sync();

    // P2: per-chunk exclusive scan of ecsbuf[1..NPAD], chunk totals -> bsumA
    for (int v = blockIdx.x; v < 196; v += nb) {
        int i = v * 256 + tid;
        int val = (i < NPAD) ? ecsbuf[1 + i] : 0;
        s[tid] = val;
        __syncthreads();
        for (int off = 1; off < 256; off <<= 1) {
            int t = (tid >= off) ? s[tid - off] : 0;
            __syncthreads();
            s[tid] += t;
            __syncthreads();
        }
        if (i < NPAD) ecsbuf[1 + i] = s[tid] - val;
        if (tid == 255) bsumA[v] = s[255];
        __syncthreads();
    }
    grid.sync();

    // P3: exclusive scan of bsumA[196] (single block; 196 <= 256)
    if (blockIdx.x == 0) {
        int val = (tid < 196) ? bsumA[tid] : 0;
        s[tid] = val;
        __syncthreads();
        for (int off = 1; off < 256; off <<= 1) {
            int t = (tid >= off) ? s[tid - off] : 0;
            __syncthreads();
            s[tid] += t;
            __syncthreads();
        }
        if (tid < 196) bsumA[tid] = s[tid] - val;
    }
    grid.sync();

    // P4: add chunk offsets
    for (int v = blockIdx.x; v < 196; v += nb) {
        int i = v * 256 + tid;
        if (i < NPAD) ecsbuf[1 + i] += bsumA[v];
    }
    grid.sync();

    // P5: invsqrt | atomic-free fill | prescale xs (virtual 0..5469)
    for (int v = blockIdx.x; v < 5470; v += nb) {
        if (v < 196) {
            int n = v * 256 + tid;
            if (n < N_NODES) {
                int di = ecsbuf[n + 2] - ecsbuf[n + 1];
                int a = deg_out[n]; if (a < 1) a = 1;
                if (di < 1) di = 1;
                inv_out[n] = 1.0f / sqrtf((float)a);
                inv_in[n]  = 1.0f / sqrtf((float)di);
            }
        } else if (v < 3321) {
            int e = (v - 196) * 256 + tid;
            if (e < N_EDGES) {
                int d = ei[N_EDGES + e];
                src_sorted[ecsbuf[1 + d] + rank[e]] = ei[e];
            }
        } else {
            int idx = (v - 3321) * 256 + tid;
            if (idx < N_NODES * 11) {
                int n = idx / 11;
                int f2 = idx - n * 11;
                int a = deg_out[n]; if (a < 1) a = 1;
                float sc = 1.0f / sqrtf((float)a);
                float2 vv = *(const float2*)&x[n * 22 + f2 * 2];
                vv.x *= sc; vv.y *= sc;
                *(float2*)&xs[n * 22 + f2 * 2] = vv;
            }
        }
    }
    grid.sync();

    // P6: layer-0 gather of xs (width 22), *inv_in, split to bf16 A (K pad 32).
    // (rank region is dead now; A_hi overwrites it.)
    for (int v = blockIdx.x; v < 3125; v += nb) {
        int idx = v * 256 + tid;
        int n = idx >> 4, f2 = idx & 15;
        if (n < N_NODES) {
            float ax = 0.f, ay = 0.f;
            if (f2 <= 10) {
                const float2* xb = (const float2*)(xs) + f2;
                int e = ecsbuf[n + 1], end = ecsbuf[n + 2];
                for (; e + 3 < end; e += 4) {
                    int s0 = src_sorted[e], s1 = src_sorted[e + 1];
                    int s2 = src_sorted[e + 2], s3 = src_sorted[e + 3];
                    float2 v0 = xb[s0 * 11], v1 = xb[s1 * 11];
                    float2 v2 = xb[s2 * 11], v3 = xb[s3 * 11];
                    ax += (v0.x + v1.x) + (v2.x + v3.x);
                    ay += (v0.y + v1.y) + (v2.y + v3.y);
                }
                for (; e < end; ++e) {
                    float2 v0 = xb[src_sorted[e] * 11];
                    ax += v0.x;
                    ay += v0.y;
                }
                float si = inv_in[n];
                ax *= si; ay *= si;
            }
            ushort2 h2, l2;
            split_bf16(ax, h2.x, l2.x);
            split_bf16(ay, h2.y, l2.y);
            *(ushort2*)&A_hi[n * 32 + f2 * 2] = h2;
            *(ushort2*)&A_lo[n * 32 + f2 * 2] = l2;
        }
    }
}

// ---------------- aggregation (width 220) ----------------
// One node per 64-lane group; lanes 0..54 own 4 features; 8 loads in flight.
// ~101 us / 325 MB FETCH = random 7-line-row fetch floor (measured r8/r10/r11).
__global__ __launch_bounds__(256) void k_agg220_split(const float* __restrict__ h,
                                                      const int* __restrict__ ecsbuf,
                                                      const int* __restrict__ srcs,
                                                      const float* __restrict__ inv_in,
                                                      unsigned short* __restrict__ A_hi,
                                                      unsigned short* __restrict__ A_lo) {
    int lane = threadIdx.x & 63;
    int n = blockIdx.x * 4 + (threadIdx.x >> 6);
    if (n >= N_NODES || lane >= 56) return;   // no barriers; early-exit safe
    size_t ob = (size_t)n * 224 + lane * 4;
    if (lane == 55) {                          // K-pad columns 220..223 = 0
        ushort4 z = {0, 0, 0, 0};
        *(ushort4*)&A_hi[ob] = z;
        *(ushort4*)&A_lo[ob] = z;
        return;
    }
    int f4 = lane * 4;
    const float* hb = h + f4;
    int e = ecsbuf[n + 1], end = ecsbuf[n + 2];
    float4 a0 = {0,0,0,0}, a1 = {0,0,0,0}, a2 = {0,0,0,0}, a3 = {0,0,0,0};
    for (; e + 7 < end; e += 8) {
        int s0 = srcs[e],     s1 = srcs[e + 1], s2 = srcs[e + 2], s3 = srcs[e + 3];
        int s4 = srcs[e + 4], s5 = srcs[e + 5], s6 = srcs[e + 6], s7 = srcs[e + 7];
        float4 v0 = *(const float4*)&hb[s0 * HSTR];
        float4 v1 = *(const float4*)&hb[s1 * HSTR];
        float4 v2 = *(const float4*)&hb[s2 * HSTR];
        float4 v3 = *(const float4*)&hb[s3 * HSTR];
        float4 v4 = *(const float4*)&hb[s4 * HSTR];
        float4 v5 = *(const float4*)&hb[s5 * HSTR];
        float4 v6 = *(const float4*)&hb[s6 * HSTR];
        float4 v7 = *(const float4*)&hb[s7 * HSTR];
        a0.x += v0.x; a0.y += v0.y; a0.z += v0.z; a0.w += v0.w;
        a1.x += v1.x; a1.y += v1.y; a1.z += v1.z; a1.w += v1.w;
        a2.x += v2.x; a2.y += v2.y; a2.z += v2.z; a2.w += v2.w;
        a3.x += v3.x; a3.y += v3.y; a3.z += v3.z; a3.w += v3.w;
        a0.x += v4.x; a0.y += v4.y; a0.z += v4.z; a0.w += v4.w;
        a1.x += v5.x; a1.y += v5.y; a1.z += v5.z; a1.w += v5.w;
        a2.x += v6.x; a2.y += v6.y; a2.z += v6.z; a2.w += v6.w;
        a3.x += v7.x; a3.y += v7.y; a3.z += v7.z; a3.w += v7.w;
    }
    for (; e + 3 < end; e += 4) {
        int s0 = srcs[e], s1 = srcs[e + 1], s2 = srcs[e + 2], s3 = srcs[e + 3];
        float4 v0 = *(const float4*)&hb[s0 * HSTR];
        float4 v1 = *(const float4*)&hb[s1 * HSTR];
        float4 v2 = *(const float4*)&hb[s2 * HSTR];
        float4 v3 = *(const float4*)&hb[s3 * HSTR];
        a0.x += v0.x; a0.y += v0.y; a0.z += v0.z; a0.w += v0.w;
        a1.x += v1.x; a1.y += v1.y; a1.z += v1.z; a1.w += v1.w;
        a2.x += v2.x; a2.y += v2.y; a2.z += v2.z; a2.w += v2.w;
        a3.x += v3.x; a3.y += v3.y; a3.z += v3.z; a3.w += v3.w;
    }
    for (; e < end; ++e) {
        float4 v = *(const float4*)&hb[srcs[e] * HSTR];
        a0.x += v.x; a0.y += v.y; a0.z += v.z; a0.w += v.w;
    }
    float sc = inv_in[n];
    float4 t;
    t.x = ((a0.x + a1.x) + (a2.x + a3.x)) * sc;
    t.y = ((a0.y + a1.y) + (a2.y + a3.y)) * sc;
    t.z = ((a0.z + a1.z) + (a2.z + a3.z)) * sc;
    t.w = ((a0.w + a1.w) + (a2.w + a3.w)) * sc;
    ushort4 h4, l4;
    split_bf16(t.x, h4.x, l4.x);
    split_bf16(t.y, h4.y, l4.y);
    split_bf16(t.z, h4.z, l4.z);
    split_bf16(t.w, h4.w, l4.w);
    *(ushort4*)&A_hi[ob] = h4;
    *(ushort4*)&A_lo[ob] = l4;
}

// layer 3: gather tmp10 (width 10, 2 MB -> L2-resident), *inv_in + bias -> d_out
__global__ void k_agg10_epi(const float* __restrict__ tmp, const int* __restrict__ ecsbuf,
                            const int* __restrict__ srcs, const float* __restrict__ inv_in,
                            const float* __restrict__ bias, float* __restrict__ out) {
    int idx = blockIdx.x * 256 + threadIdx.x;
    if (idx >= N_NODES * 5) return;
    int n = idx / 5;
    int f2 = idx - n * 5;
    const float2* tb = (const float2*)(tmp) + f2;
    float ax = 0.f, ay = 0.f;
    int e = ecsbuf[n + 1], end = ecsbuf[n + 2];
    for (; e + 1 < end; e += 2) {
        float2 v0 = tb[srcs[e] * 5];
        float2 v1 = tb[srcs[e + 1] * 5];
        ax += v0.x + v1.x;
        ay += v0.y + v1.y;
    }
    if (e < end) {
        float2 v0 = tb[srcs[e] * 5];
        ax += v0.x;
        ay += v0.y;
    }
    float si = inv_in[n];
    float2 o;
    o.x = ax * si + bias[f2 * 2];
    o.y = ay * si + bias[f2 * 2 + 1];
    *(float2*)&out[n * 10 + f2 * 2] = o;
}

// ---------------- MFMA split-bf16 GEMM, 2 row-tiles per wave ----------------
// D = A@W via A_hi*W_hi + A_hi*W_lo + A_lo*W_hi (~fp32 precision).
// FUSE_W3 (layer 2): h2 never touches memory; p10 accumulated per col-tile,
// shfl_xor tree over the 16 lanes of each row, lane lrow==0 stores tmp10.
template <int KSTEPS, int LDA, bool FUSE_W3>
__global__ __launch_bounds__(256) void k_gemm_mfma(const unsigned short* __restrict__ A_hi,
                                                   const unsigned short* __restrict__ A_lo,
                                                   const unsigned short* __restrict__ WT_hi,
                                                   const unsigned short* __restrict__ WT_lo,
                                                   const float* __restrict__ bias,
                                                   const float* __restrict__ post,
                                                   float* __restrict__ out,
                                                   const float* __restrict__ W3,
                                                   float* __restrict__ tmp) {
    int tid = threadIdx.x;
    int l = tid & 63, w = tid >> 6;
    int lrow = l & 15, q = l >> 4;
    int rt = blockIdx.x * 128 + w * 32;

    const unsigned short* pa0h = A_hi + (size_t)(rt + lrow) * LDA + q * 8;
    const unsigned short* pa0l = A_lo + (size_t)(rt + lrow) * LDA + q * 8;
    const unsigned short* pa1h = pa0h + 16 * LDA;
    const unsigned short* pa1l = pa0l + 16 * LDA;

    f32x4 acc0[14], acc1[14];
#pragma unroll
    for (int ct = 0; ct < 14; ++ct) {
        acc0[ct] = (f32x4){0.f, 0.f, 0.f, 0.f};
        acc1[ct] = (f32x4){0.f, 0.f, 0.f, 0.f};
    }

#pragma unroll
    for (int ks = 0; ks < KSTEPS; ++ks) {
        int k0 = ks * 32;
        short8 ah0 = *(const short8*)(const void*)(pa0h + k0);
        short8 al0 = *(const short8*)(const void*)(pa0l + k0);
        short8 ah1 = *(const short8*)(const void*)(pa1h + k0);
        short8 al1 = *(const short8*)(const void*)(pa1l + k0);
#pragma unroll
        for (int ct = 0; ct < 14; ++ct) {
            size_t boff = (size_t)(ct * 16 + lrow) * LDA + q * 8 + k0;
            short8 bh = *(const short8*)(const void*)(WT_hi + boff);
            short8 bl = *(const short8*)(const void*)(WT_lo + boff);
            acc0[ct] = mfma16(ah0, bh, acc0[ct]);
            acc0[ct] = mfma16(ah0, bl, acc0[ct]);
            acc0[ct] = mfma16(al0, bh, acc0[ct]);
            acc1[ct] = mfma16(ah1, bh, acc1[ct]);
            acc1[ct] = mfma16(ah1, bl, acc1[ct]);
            acc1[ct] = mfma16(al1, bh, acc1[ct]);
        }
    }

    float pv0[4], pv1[4];
#pragma unroll
    for (int r = 0; r < 4; ++r) {
        int r0 = rt + q * 4 + r;
        int r1 = r0 + 16;
        pv0[r] = (r0 < N_NODES) ? post[r0] : 0.f;
        pv1[r] = (r1 < N_NODES) ? post[r1] : 0.f;
    }

    if (!FUSE_W3) {
#pragma unroll
        for (int ct = 0; ct < 14; ++ct) {
            int col = ct * 16 + lrow;
            if (col >= 220) continue;
            float bv = bias[col];
#pragma unroll
            for (int r = 0; r < 4; ++r) {
                int r0 = rt + q * 4 + r;
                int r1 = r0 + 16;
                if (r0 < N_NODES)
                    out[(size_t)r0 * HSTR + col] = pv0[r] * fast_tanh(acc0[ct][r] + bv);
                if (r1 < N_NODES)
                    out[(size_t)r1 * HSTR + col] = pv1[r] * fast_tanh(acc1[ct][r] + bv);
            }
        }
    } else {
#pragma unroll
        for (int half = 0; half < 2; ++half) {
            const f32x4* acc = half ? acc1 : acc0;
            const float* pv  = half ? pv1 : pv0;
            int rbase = rt + half * 16;
            float p[4][10];
#pragma unroll
            for (int r = 0; r < 4; ++r)
#pragma unroll
                for (int j = 0; j < 10; ++j) p[r][j] = 0.f;
#pragma unroll
            for (int ct = 0; ct < 14; ++ct) {
                int col = ct * 16 + lrow;
                bool cok = col < 220;
                float bv = cok ? bias[col] : 0.f;
                float w3v[10];
                if (cok) {
                    const float2* wp = (const float2*)&W3[col * 10];
#pragma unroll
                    for (int j2 = 0; j2 < 5; ++j2) {
                        float2 t = wp[j2];
                        w3v[2 * j2] = t.x;
                        w3v[2 * j2 + 1] = t.y;
                    }
                } else {
#pragma unroll
                    for (int j = 0; j < 10; ++j) w3v[j] = 0.f;
                }
#pragma unroll
                for (int r = 0; r < 4; ++r) {
                    float h2 = pv[r] * fast_tanh(acc[ct][r] + bv);
#pragma unroll
                    for (int j = 0; j < 10; ++j) p[r][j] += h2 * w3v[j];
                }
            }
#pragma unroll
            for (int r = 0; r < 4; ++r)
#pragma unroll
                for (int j = 0; j < 10; ++j) {
                    float v = p[r][j];
                    v += __shfl_xor(v, 1, 64);
                    v += __shfl_xor(v, 2, 64);
                    v += __shfl_xor(v, 4, 64);
                    v += __shfl_xor(v, 8, 64);
                    p[r][j] = v;
                }
            if (lrow == 0) {
#pragma unroll
                for (int r = 0; r < 4; ++r) {
                    int row = rbase + q * 4 + r;
                    if (row < N_NODES) {
#pragma unroll
                        for (int j2 = 0; j2 < 5; ++j2) {
                            float2 o = {p[r][2 * j2], p[r][2 * j2 + 1]};
                            *(float2*)&tmp[(size_t)row * 10 + 2 * j2] = o;
                        }
                    }
                }
            }
        }
    }
}

// ---------------- launch ----------------

extern "C" void kernel_launch(void* const* d_in, const int* in_sizes, int n_in,
                              void* d_out, int out_size, void* d_ws, size_t ws_size,
                              hipStream_t stream) {
    const float* x  = (const float*)d_in[0];
    const float* W0 = (const float*)d_in[1];
    const float* b0 = (const float*)d_in[2];
    const float* W1 = (const float*)d_in[3];
    const float* b1 = (const float*)d_in[4];
    const float* W2 = (const float*)d_in[5];
    const float* b2 = (const float*)d_in[6];
    const float* W3 = (const float*)d_in[7];
    const float* b3 = (const float*)d_in[8];
    const int*   ei = (const int*)d_in[9];
    float* out = (float*)d_out;

    int* ws = (int*)d_ws;
    int* ecsbuf     = ws + O_ECS;
    float* inv_out  = (float*)(ws + O_INVOUT);
    float* inv_in   = (float*)(ws + O_INVIN);
    int* src_sorted = ws + O_SRCS;
    unsigned short* wt0h = (unsigned short*)(ws + O_WT0H);
    unsigned short* wt0l = (unsigned short*)(ws + O_WT0L);
    unsigned short* wt1h = (unsigned short*)(ws + O_WT1H);
    unsigned short* wt1l = (unsigned short*)(ws + O_WT1L);
    unsigned short* wt2h = (unsigned short*)(ws + O_WT2H);
    unsigned short* wt2l = (unsigned short*)(ws + O_WT2L);
    unsigned short* ahi  = (unsigned short*)(ws + O_AHI);
    unsigned short* alo  = (unsigned short*)(ws + O_ALO);
    float* hbuf  = (float*)(ws + O_HBUF);
    float* tmp10 = (float*)(ws + O_TMP10);

    // cooperative front-end: CSR build + weight splits + layer-0 gather/split.
    // grid sized to guaranteed co-residency (host query; no stream ops).
    int maxb = 0;
    hipOccupancyMaxActiveBlocksPerMultiprocessor(&maxb, k_front_coop, 256, 0);
    int nb = maxb * 256;
    if (nb > 2048) nb = 2048;
    if (nb < 256) nb = 256;
    void* cargs[] = {(void*)&ei, (void*)&x, (void*)&W0, (void*)&W1, (void*)&W2, (void*)&ws};
    hipLaunchCooperativeKernel((void*)k_front_coop, dim3(nb), dim3(256), cargs, 0, stream);

    int gemm_grid = (NPAD + 127) / 128;      // 392
    int agg_grid  = (N_NODES + 3) / 4;       // 12500

    // ---- layer 0 GEMM (A built by coop P6)
    k_gemm_mfma<1, 32, false><<<gemm_grid, 256, 0, stream>>>(
        ahi, alo, wt0h, wt0l, b0, inv_out, hbuf, nullptr, nullptr);

    // ---- layer 1
    k_agg220_split<<<agg_grid, 256, 0, stream>>>(hbuf, ecsbuf, src_sorted, inv_in, ahi, alo);
    k_gemm_mfma<7, 224, false><<<gemm_grid, 256, 0, stream>>>(
        ahi, alo, wt1h, wt1l, b1, inv_out, hbuf, nullptr, nullptr);

    // ---- layer 2 (+ fused W3 projection)
    k_agg220_split<<<agg_grid, 256, 0, stream>>>(hbuf, ecsbuf, src_sorted, inv_in, ahi, alo);
    k_gemm_mfma<7, 224, true><<<gemm_grid, 256, 0, stream>>>(
        ahi, alo, wt2h, wt2l, b2, inv_out, nullptr, W3, tmp10);

    // ---- layer 3
    k_agg10_epi<<<(N_NODES * 5 + 255) / 256, 256, 0, stream>>>(
        tmp10, ecsbuf, src_sorted, inv_in, b3, out);
}